// Round 20
// baseline (172.982 us; speedup 1.0000x reference)
//
#include <hip/hip_runtime.h>
#include <math.h>

#define N_ATOMS 4096
#define F 128
#define K 8
#define KF 1024           // K*F
#define KFF 131072        // K*F*F
#define FF 16384          // F*F
#define NF 524288         // N*F
#define NKF 4194304       // N*K*F
#define MAXNB 128
#define RMAX 5.0f
#define RMAX2 25.0f
#define GAMMA 2.56f       // (K/RMAX)^2
#define MU_STEP 0.714285714285714f  // RMAX/(K-1)
#define PI_F 3.14159265358979323846f
#define POR (PI_F / RMAX)

typedef __bf16 bf16x8_t __attribute__((ext_vector_type(8)));
typedef float f32x4_t __attribute__((ext_vector_type(4)));
typedef unsigned short u16x8_t __attribute__((ext_vector_type(8)));
typedef unsigned short u16x4_t __attribute__((ext_vector_type(4)));

__device__ __forceinline__ float sigm(float x){ return 1.0f/(1.0f + expf(-x)); }
__device__ __forceinline__ unsigned short f2bf(float x){
  unsigned int u = __float_as_uint(x);
  u += 0x7fff + ((u >> 16) & 1);
  return (unsigned short)(u >> 16);
}
__device__ __forceinline__ float bf2f(unsigned short b){
  return __uint_as_float(((unsigned int)b) << 16);
}

// ======================= device bodies ======================================

// agg: A[a,k,f] = sum_n rbf_k(d_an) h[j_n,f] -> bf16 A-fragments (h in bf16)
__device__ __forceinline__ void agg_body(int a, int t,
        const unsigned short* __restrict__ h_in, const int* __restrict__ nb_idx,
        const float* __restrict__ rbf, const int* __restrict__ nb_cnt,
        unsigned short* __restrict__ Af){
  int grp = t >> 6, lane = t & 63;
  __shared__ int s_j[MAXNB];
  __shared__ float s_acc[4][8][128];
  int cnt = nb_cnt[a];
  for (int idx = t; idx < cnt; idx += 256) s_j[idx] = nb_idx[a*MAXNB + idx];
  __syncthreads();
  float2 acc[8];
  #pragma unroll
  for (int k = 0; k < 8; k++) acc[k] = {0.f, 0.f};
  const float4* rb = (const float4*)(rbf + (size_t)a*MAXNB*8);
  for (int n = grp; n < cnt; n += 4){
    unsigned int pv = *(const unsigned int*)&h_in[(size_t)s_j[n]*F + lane*2];
    float hx = __uint_as_float(pv << 16);
    float hy = __uint_as_float(pv & 0xffff0000u);
    float4 r0 = rb[n*2], r1 = rb[n*2+1];
    acc[0].x += r0.x*hx; acc[0].y += r0.x*hy;
    acc[1].x += r0.y*hx; acc[1].y += r0.y*hy;
    acc[2].x += r0.z*hx; acc[2].y += r0.z*hy;
    acc[3].x += r0.w*hx; acc[3].y += r0.w*hy;
    acc[4].x += r1.x*hx; acc[4].y += r1.x*hy;
    acc[5].x += r1.y*hx; acc[5].y += r1.y*hy;
    acc[6].x += r1.z*hx; acc[6].y += r1.z*hy;
    acc[7].x += r1.w*hx; acc[7].y += r1.w*hy;
  }
  #pragma unroll
  for (int k = 0; k < 8; k++)
    *(float2*)&s_acc[grp][k][lane*2] = acc[k];
  __syncthreads();
  int k = t >> 5, q = t & 31;
  int f0 = q*4;
  float v[4];
  #pragma unroll
  for (int i = 0; i < 4; i++){
    int f = f0 + i;
    v[i] = s_acc[0][k][f] + s_acc[1][k][f] + s_acc[2][k][f] + s_acc[3][k][f];
  }
  int lf = (a & 15) | (((f0 >> 3) & 3) << 4);
  int kc = k*4 + (f0 >> 5);
  size_t flat = (size_t)(a >> 4)*16384 + ((size_t)kc*64 + lf)*8 + (f0 & 7);
  u16x4_t o;
  o[0] = f2bf(v[0]); o[1] = f2bf(v[1]); o[2] = f2bf(v[2]); o[3] = f2bf(v[3]);
  *(u16x4_t*)(Af + flat) = o;
}

__device__ __forceinline__ void mgemm_bwd_body(int bx, int t,
        const unsigned short* __restrict__ Gf, const unsigned short* __restrict__ Bf,
        unsigned short* __restrict__ dAbf){
  int l = t & 63, w = t >> 6;
  int rtile = (bx & 63)*4 + w;
  int nt0 = (bx >> 6)*8;
  f32x4_t acc[8];
  #pragma unroll
  for (int i = 0; i < 8; i++) acc[i] = (f32x4_t){0.f,0.f,0.f,0.f};
  const unsigned short* Ab = Gf + (size_t)rtile*2048 + l*8;
  const unsigned short* Bb = Bf + l*8;
  #pragma unroll
  for (int kc = 0; kc < 4; kc++){
    bf16x8_t a = *(const bf16x8_t*)(Ab + kc*512);
    #pragma unroll
    for (int nt = 0; nt < 8; nt++){
      bf16x8_t b = *(const bf16x8_t*)(Bb + (kc*64 + nt0 + nt)*512);
      acc[nt] = __builtin_amdgcn_mfma_f32_16x16x32_bf16(a, b, acc[nt], 0, 0, 0);
    }
  }
  int row0 = rtile*16 + (l >> 4)*4;
  int col = l & 15;
  #pragma unroll
  for (int nt = 0; nt < 8; nt++){
    #pragma unroll
    for (int r = 0; r < 4; r++)
      dAbf[(size_t)(row0+r)*1024 + (nt0+nt)*16 + col] = f2bf(acc[nt][r]);
  }
}

// ======================= kernels ============================================

// ---- mega-prep: [0,2048) nb scan (2 atoms x 2 j-half waves) + rbf tail;
//                 [2048,2112) wprep; rest embed -> h0bf
__global__ __launch_bounds__(256) void k_prep(const float* __restrict__ pos,
        const int* __restrict__ z, const float* __restrict__ embed,
        const float* __restrict__ W1, const float* __restrict__ W2,
        const float* __restrict__ Wr1,
        int* __restrict__ nb_idx, float* __restrict__ nb_d, int* __restrict__ nb_cnt,
        float* __restrict__ rbf, float* __restrict__ drbf,
        unsigned short* __restrict__ WF1, unsigned short* __restrict__ WF2,
        unsigned short* __restrict__ WDF2, unsigned short* __restrict__ WTF1,
        unsigned short* __restrict__ WTF2, unsigned short* __restrict__ Wr1F,
        unsigned short* __restrict__ Wr1TF,
        unsigned short* __restrict__ h0bf){
  int t = threadIdx.x;
  if (blockIdx.x < 2048){
    int w2 = t >> 7;          // atom sub-index
    int half = (t >> 6) & 1;  // j half
    int lane = t & 63;
    int i = blockIdx.x*2 + w2;
    __shared__ float spx[2][256], spy[2][256], spz[2][256], ssq[2][256];
    __shared__ int s_jl[2][2][128];
    __shared__ float s_dl[2][2][128];
    __shared__ int s_cnt[2][2];
    float pix = pos[3*i], piy = pos[3*i+1], piz = pos[3*i+2];
    float sqi = pix*pix + piy*piy + piz*piz;
    int count = 0;
    for (int it = 0; it < 8; it++){
      __syncthreads();
      {
        int j0 = it*256 + t;
        float px = pos[3*j0], py = pos[3*j0+1], pz = pos[3*j0+2];
        spx[0][t] = px; spy[0][t] = py; spz[0][t] = pz;
        ssq[0][t] = px*px + py*py + pz*pz;
        int j1 = 2048 + it*256 + t;
        px = pos[3*j1]; py = pos[3*j1+1]; pz = pos[3*j1+2];
        spx[1][t] = px; spy[1][t] = py; spz[1][t] = pz;
        ssq[1][t] = px*px + py*py + pz*pz;
      }
      __syncthreads();
      #pragma unroll
      for (int c = 0; c < 4; c++){
        int jj = c*64 + lane;
        int j = half*2048 + it*256 + jj;
        float dot = pix*spx[half][jj] + piy*spy[half][jj] + piz*spz[half][jj];
        float d2 = sqi + ssq[half][jj] - 2.0f*dot;
        bool pred = (j != i) && (d2 > 0.0f) && (d2 < RMAX2);
        unsigned long long m = __ballot(pred);
        int off = __popcll(m & ((1ull << lane) - 1ull));
        if (pred){
          int p = count + off;
          if (p < 128){ s_jl[w2][half][p] = j; s_dl[w2][half][p] = sqrtf(d2); }
        }
        count += __popcll(m);
      }
    }
    if (lane == 0) s_cnt[w2][half] = count;
    __syncthreads();
    int c0 = s_cnt[w2][0]; if (c0 > 128) c0 = 128;
    int c1 = s_cnt[w2][1]; if (c1 > 128) c1 = 128;
    int cc = c0 + c1; if (cc > MAXNB) cc = MAXNB;
    int tia = t & 127;
    if (tia == 0) nb_cnt[i] = cc;
    for (int n = tia; n < cc; n += 128){
      int j; float d;
      if (n < c0){ j = s_jl[w2][0][n]; d = s_dl[w2][0][n]; }
      else       { j = s_jl[w2][1][n - c0]; d = s_dl[w2][1][n - c0]; }
      nb_idx[i*MAXNB + n] = j;
      nb_d[i*MAXNB + n] = d;
      float ph = POR*d;
      float cph, sph;
      __sincosf(ph, &sph, &cph);
      float env = 0.5f*(cph + 1.0f);
      float denv = -0.5f*POR*sph;
      float rr[8], dd[8];
      #pragma unroll
      for (int k = 0; k < 8; k++){
        float dm = d - MU_STEP*(float)k;
        float G = expf(-GAMMA*dm*dm);
        rr[k] = G*env;
        dd[k] = G*(-2.0f*GAMMA*dm*env + denv);
      }
      float4* rb = (float4*)(rbf + ((size_t)i*MAXNB + n)*8);
      rb[0] = {rr[0],rr[1],rr[2],rr[3]};
      rb[1] = {rr[4],rr[5],rr[6],rr[7]};
      float4* db = (float4*)(drbf + ((size_t)i*MAXNB + n)*8);
      db[0] = {dd[0],dd[1],dd[2],dd[3]};
      db[1] = {dd[4],dd[5],dd[6],dd[7]};
    }
    return;
  }
  if (blockIdx.x >= 2112){
    int idx = (blockIdx.x - 2112)*256 + t;
    int i = idx >> 7, f = idx & 127;
    h0bf[idx] = f2bf(embed[z[i]*F + f]);
    return;
  }
  int idx = (blockIdx.x - 2048)*256 + t;   // 0..16383
  int l = idx & 63;
  int hi = idx >> 6;
  {
    int kc = hi >> 3, nt = hi & 7;
    int kfb = kc*32 + ((l>>4)&3)*8;
    int g = nt*16 + (l&15);
    u16x8_t v1, v2, vd;
    #pragma unroll
    for (int j = 0; j < 8; j++){
      int kf = kfb + j;
      v1[j] = f2bf(W1[kf*128 + g]);
      v2[j] = f2bf(W2[kf*128 + g]);
      vd[j] = f2bf(W2[(kf>>7)*FF + g*F + (kf&127)]);
    }
    *(u16x8_t*)(WF1 + idx*8) = v1;
    *(u16x8_t*)(WF2 + idx*8) = v2;
    *(u16x8_t*)(WDF2 + idx*8) = vd;
  }
  {
    int kc = hi >> 6, nt = hi & 63;
    int gb = kc*32 + ((l>>4)&3)*8;
    int kf = nt*16 + (l&15);
    u16x8_t t1, t2;
    #pragma unroll
    for (int j = 0; j < 8; j++){
      int g = gb + j;
      t1[j] = f2bf(W1[kf*128 + g]);
      t2[j] = f2bf(W2[kf*128 + g]);
    }
    *(u16x8_t*)(WTF1 + idx*8) = t1;
    *(u16x8_t*)(WTF2 + idx*8) = t2;
  }
  {
    int m = idx >> 9;
    int ll = (idx >> 3) & 63;
    int j = idx & 7;
    int kc = m >> 3, nt = m & 7;
    int kf = kc*32 + ((ll>>4)&3)*8 + j;
    int g = nt*16 + (ll&15);
    Wr1F[idx]  = f2bf(Wr1[kf*128 + g]);
    Wr1TF[idx] = f2bf(Wr1[g*128 + kf]);
  }
}

// ---- layer-1 agg: h0 = embed[z[j]] gathered from LDS-staged embed table ----
__global__ __launch_bounds__(256) void k_agg0(const int* __restrict__ z,
        const float* __restrict__ embed, const int* __restrict__ nb_idx,
        const float* __restrict__ rbf, const int* __restrict__ nb_cnt,
        unsigned short* __restrict__ Af){
  int a = blockIdx.x;
  int t = threadIdx.x;
  int grp = t >> 6, lane = t & 63;
  __shared__ int s_j[MAXNB];
  __shared__ float s_emb[1280];     // 10 x 128 f32 = 5 KB
  __shared__ float s_acc[4][8][128];
  int cnt = nb_cnt[a];
  for (int idx = t; idx < 1280; idx += 256) s_emb[idx] = embed[idx];
  for (int idx = t; idx < cnt; idx += 256) s_j[idx] = nb_idx[a*MAXNB + idx];
  __syncthreads();
  float2 acc[8];
  #pragma unroll
  for (int k = 0; k < 8; k++) acc[k] = {0.f, 0.f};
  const float4* rb = (const float4*)(rbf + (size_t)a*MAXNB*8);
  for (int n = grp; n < cnt; n += 4){
    int zj = z[s_j[n]];
    float2 hv = *(const float2*)&s_emb[zj*128 + lane*2];
    float4 r0 = rb[n*2], r1 = rb[n*2+1];
    acc[0].x += r0.x*hv.x; acc[0].y += r0.x*hv.y;
    acc[1].x += r0.y*hv.x; acc[1].y += r0.y*hv.y;
    acc[2].x += r0.z*hv.x; acc[2].y += r0.z*hv.y;
    acc[3].x += r0.w*hv.x; acc[3].y += r0.w*hv.y;
    acc[4].x += r1.x*hv.x; acc[4].y += r1.x*hv.y;
    acc[5].x += r1.y*hv.x; acc[5].y += r1.y*hv.y;
    acc[6].x += r1.z*hv.x; acc[6].y += r1.z*hv.y;
    acc[7].x += r1.w*hv.x; acc[7].y += r1.w*hv.y;
  }
  #pragma unroll
  for (int k = 0; k < 8; k++)
    *(float2*)&s_acc[grp][k][lane*2] = acc[k];
  __syncthreads();
  int k = t >> 5, q = t & 31;
  int f0 = q*4;
  float v[4];
  #pragma unroll
  for (int i = 0; i < 4; i++){
    int f = f0 + i;
    v[i] = s_acc[0][k][f] + s_acc[1][k][f] + s_acc[2][k][f] + s_acc[3][k][f];
  }
  int lf = (a & 15) | (((f0 >> 3) & 3) << 4);
  int kc = k*4 + (f0 >> 5);
  size_t flat = (size_t)(a >> 4)*16384 + ((size_t)kc*64 + lf)*8 + (f0 & 7);
  u16x4_t o;
  o[0] = f2bf(v[0]); o[1] = f2bf(v[1]); o[2] = f2bf(v[2]); o[3] = f2bf(v[3]);
  *(u16x4_t*)(Af + flat) = o;
}

// ---- standalone agg (bf16 h input) -----------------------------------------
__global__ __launch_bounds__(256) void k_agg(const unsigned short* __restrict__ h_in,
        const int* __restrict__ nb_idx, const float* __restrict__ rbf,
        const int* __restrict__ nb_cnt, unsigned short* __restrict__ Af){
  agg_body(blockIdx.x, threadIdx.x, h_in, nb_idx, rbf, nb_cnt, Af);
}

// ---- merged: [0,512) mgemm_bwd(dA2); [512, 4608) agg(g2bf) -----------------
__global__ __launch_bounds__(256) void k_bwdmix(const unsigned short* __restrict__ Gf,
        const unsigned short* __restrict__ Bf, unsigned short* __restrict__ dAbf,
        const unsigned short* __restrict__ g2bf, const int* __restrict__ nb_idx,
        const float* __restrict__ rbf, const int* __restrict__ nb_cnt,
        unsigned short* __restrict__ Af){
  if (blockIdx.x < 512){
    mgemm_bwd_body(blockIdx.x, threadIdx.x, Gf, Bf, dAbf);
    return;
  }
  agg_body(blockIdx.x - 512, threadIdx.x, g2bf, nb_idx, rbf, nb_cnt, Af);
}

// ---- standalone mgemm_bwd --------------------------------------------------
__global__ __launch_bounds__(256) void k_mgemm_bwd(const unsigned short* __restrict__ Gf,
        const unsigned short* __restrict__ Bf, unsigned short* __restrict__ dAbf){
  mgemm_bwd_body(blockIdx.x, threadIdx.x, Gf, Bf, dAbf);
}

// ---- full-K MFMA GEMM fwd-shape + fused epilogue (addv in bf16) ------------
// mode 0: m = acc + addv; out_m = m (f32); out_hbf = bf16(silu(m))
// mode 1: g1 = (acc + addv)*silu'(msrc) -> out_frag (bf16 A-frag layout)
__global__ __launch_bounds__(256) void k_mgemm_fwd(const unsigned short* __restrict__ Af,
        const unsigned short* __restrict__ Bf, const unsigned short* __restrict__ addv,
        const float* __restrict__ msrc, float* __restrict__ out_m,
        unsigned short* __restrict__ out_hbf, unsigned short* __restrict__ out_frag,
        int mode){
  int t = threadIdx.x;
  int l = t & 63, w = t >> 6;
  int rtile = blockIdx.x;
  int nt = blockIdx.y*4 + w;
  f32x4_t accA = (f32x4_t){0.f,0.f,0.f,0.f};
  f32x4_t accB = (f32x4_t){0.f,0.f,0.f,0.f};
  const unsigned short* Ab = Af + (size_t)rtile*16384 + l*8;
  const unsigned short* Bb = Bf + l*8;
  #pragma unroll
  for (int kc = 0; kc < 32; kc += 2){
    bf16x8_t a0 = *(const bf16x8_t*)(Ab + kc*512);
    bf16x8_t b0 = *(const bf16x8_t*)(Bb + (kc*8 + nt)*512);
    bf16x8_t a1 = *(const bf16x8_t*)(Ab + (kc+1)*512);
    bf16x8_t b1 = *(const bf16x8_t*)(Bb + ((kc+1)*8 + nt)*512);
    accA = __builtin_amdgcn_mfma_f32_16x16x32_bf16(a0, b0, accA, 0, 0, 0);
    accB = __builtin_amdgcn_mfma_f32_16x16x32_bf16(a1, b1, accB, 0, 0, 0);
  }
  f32x4_t acc = accA + accB;
  int row0 = rtile*16 + (l >> 4)*4;
  int col = nt*16 + (l & 15);
  if (mode == 0){
    #pragma unroll
    for (int r = 0; r < 4; r++){
      int i = row0 + r;
      float m = acc[r] + bf2f(addv[(size_t)i*F + col]);
      out_m[(size_t)i*F + col] = m;
      out_hbf[(size_t)i*F + col] = f2bf(m*sigm(m));
    }
  } else {
    int kc2 = col >> 5;
    int lfr0 = (((col >> 3) & 3) << 4);
    int jj = col & 7;
    #pragma unroll
    for (int r = 0; r < 4; r++){
      int i = row0 + r;
      float mm = msrc[(size_t)i*F + col];
      float sg = sigm(mm);
      float gv = (acc[r] + bf2f(addv[(size_t)i*F + col]))*(sg*(1.f + mm*(1.f - sg)));
      int lfr = (i & 15) | lfr0;
      size_t flat = (((size_t)(i>>4)*4 + kc2)*64 + lfr)*8 + jj;
      out_frag[flat] = f2bf(gv);
    }
  }
}

// ------- MFMA readout: 256 thr = 4 waves per 16 atoms; waves split nt -------
__global__ __launch_bounds__(256) void k_readout(const unsigned short* __restrict__ h2bf,
        const float* __restrict__ m2, const unsigned short* __restrict__ Wr1F,
        const unsigned short* __restrict__ Wr1TF, const float* __restrict__ Wr2,
        float* __restrict__ e_at,
        unsigned short* __restrict__ g2bf, unsigned short* __restrict__ g2frag){
  int a0 = blockIdx.x*16;
  int t = threadIdx.x;
  int wv = t >> 6, l = t & 63;
  int rl = l & 15;
  __shared__ unsigned short sdu[16][136];
  __shared__ float ered[4][16];
  f32x4_t acc[2];
  acc[0] = (f32x4_t){0.f,0.f,0.f,0.f};
  acc[1] = (f32x4_t){0.f,0.f,0.f,0.f};
  #pragma unroll
  for (int kc = 0; kc < 4; kc++){
    bf16x8_t af = *(const bf16x8_t*)(h2bf + (size_t)(a0+rl)*F + kc*32 + ((l>>4)&3)*8);
    #pragma unroll
    for (int q = 0; q < 2; q++){
      int nt = wv*2 + q;
      bf16x8_t bf = *(const bf16x8_t*)(Wr1F + ((kc*8+nt)*64 + l)*8);
      acc[q] = __builtin_amdgcn_mfma_f32_16x16x32_bf16(af, bf, acc[q], 0, 0, 0);
    }
  }
  float epart[4] = {0.f,0.f,0.f,0.f};
  #pragma unroll
  for (int q = 0; q < 2; q++){
    int nt = wv*2 + q;
    float w2 = Wr2[nt*16 + rl];
    #pragma unroll
    for (int r = 0; r < 4; r++){
      float u = acc[q][r];
      float sg = sigm(u);
      epart[r] += u*sg*w2;
      sdu[(l>>4)*4 + r][nt*16 + rl] = f2bf(w2*(sg*(1.f + u*(1.f - sg))));
    }
  }
  #pragma unroll
  for (int o = 1; o < 16; o <<= 1){
    #pragma unroll
    for (int r = 0; r < 4; r++) epart[r] += __shfl_xor(epart[r], o);
  }
  if (rl == 0){
    #pragma unroll
    for (int r = 0; r < 4; r++) ered[wv][(l>>4)*4 + r] = epart[r];
  }
  __syncthreads();
  if (t < 16) e_at[a0 + t] = ered[0][t] + ered[1][t] + ered[2][t] + ered[3][t];
  f32x4_t acc2[2];
  acc2[0] = (f32x4_t){0.f,0.f,0.f,0.f};
  acc2[1] = (f32x4_t){0.f,0.f,0.f,0.f};
  #pragma unroll
  for (int kc = 0; kc < 4; kc++){
    bf16x8_t af = *(const bf16x8_t*)&sdu[rl][kc*32 + ((l>>4)&3)*8];
    #pragma unroll
    for (int q = 0; q < 2; q++){
      int nt = wv*2 + q;
      bf16x8_t bf = *(const bf16x8_t*)(Wr1TF + ((kc*8+nt)*64 + l)*8);
      acc2[q] = __builtin_amdgcn_mfma_f32_16x16x32_bf16(af, bf, acc2[q], 0, 0, 0);
    }
  }
  #pragma unroll
  for (int q = 0; q < 2; q++){
    int nt = wv*2 + q;
    int g = nt*16 + rl;
    int kc2 = g >> 5;
    int lfr0 = (((g >> 3) & 3) << 4);
    int jj = g & 7;
    #pragma unroll
    for (int r = 0; r < 4; r++){
      int a = a0 + (l>>4)*4 + r;
      float mm = m2[(size_t)a*F + g];
      float sg = sigm(mm);
      float gv = acc2[q][r]*(sg*(1.f + mm*(1.f - sg)));
      unsigned short gb = f2bf(gv);
      g2bf[(size_t)a*F + g] = gb;
      int lfr = (a & 15) | lfr0;
      g2frag[(((size_t)(a>>4)*4 + kc2)*64 + lfr)*8 + jj] = gb;
    }
  }
}

// ------- per-edge scalar via MFMA -------------------------------------------
__global__ __launch_bounds__(256) void k_edge(const unsigned short* __restrict__ dA2bf,
        const unsigned short* __restrict__ dA1bf, const unsigned short* __restrict__ h1bf,
        const unsigned short* __restrict__ h0bf, const float* __restrict__ drbf,
        const int* __restrict__ nb_idx, const int* __restrict__ nb_cnt,
        float* __restrict__ edge_s){
  int a = blockIdx.x;
  int t = threadIdx.x;
  int w = t >> 6, l = t & 63;
  __shared__ int s_j[MAXNB];
  int cnt = nb_cnt[a];
  for (int idx = t; idx < cnt; idx += 256) s_j[idx] = nb_idx[a*MAXNB + idx];
  int r = l & 15;
  int sel = (l >> 4) & 3;
  u16x8_t a2u[4], a1u[4];
  #pragma unroll
  for (int kc = 0; kc < 4; kc++){
    u16x8_t v2 = {0,0,0,0,0,0,0,0};
    u16x8_t v1 = {0,0,0,0,0,0,0,0};
    if (r < 8){
      v2 = *(const u16x8_t*)(dA2bf + (size_t)a*KF + r*F + kc*32 + sel*8);
      v1 = *(const u16x8_t*)(dA1bf + (size_t)a*KF + r*F + kc*32 + sel*8);
    }
    a2u[kc] = v2; a1u[kc] = v1;
  }
  __syncthreads();
  for (int n0 = w*16; n0 < cnt; n0 += 64){
    int nl = n0 + r;
    int nls = nl < cnt ? nl : cnt - 1;
    int j = s_j[nls];
    const unsigned short* h1p = h1bf + (size_t)j*F + sel*8;
    const unsigned short* h0p = h0bf + (size_t)j*F + sel*8;
    f32x4_t acc = (f32x4_t){0.f,0.f,0.f,0.f};
    #pragma unroll
    for (int kc = 0; kc < 4; kc++){
      bf16x8_t b = *(const bf16x8_t*)(h1p + kc*32);
      acc = __builtin_amdgcn_mfma_f32_16x16x32_bf16(*(const bf16x8_t*)&a2u[kc], b, acc, 0, 0, 0);
    }
    #pragma unroll
    for (int kc = 0; kc < 4; kc++){
      bf16x8_t b = *(const bf16x8_t*)(h0p + kc*32);
      acc = __builtin_amdgcn_mfma_f32_16x16x32_bf16(*(const bf16x8_t*)&a1u[kc], b, acc, 0, 0, 0);
    }
    int krow = (l >> 4) * 4;
    float part = 0.f;
    if (krow < 8){
      float4 dr = *(const float4*)(drbf + ((size_t)a*MAXNB + nls)*8 + krow);
      part = acc[0]*dr.x + acc[1]*dr.y + acc[2]*dr.z + acc[3]*dr.w;
    }
    part += __shfl_xor(part, 16);
    if (l < 16 && nl < cnt) edge_s[a*MAXNB + nl] = part;
  }
}

// ------- force (4 atoms/block) + energy sum ---------------------------------
__global__ __launch_bounds__(256) void k_force(const float* __restrict__ pos,
        const int* __restrict__ nb_idx, const float* __restrict__ nb_d,
        const int* __restrict__ nb_cnt, const float* __restrict__ edge_s,
        const float* __restrict__ e_at, float* __restrict__ out){
  int bw = threadIdx.x >> 6, lane = threadIdx.x & 63;
  if (blockIdx.x == N_ATOMS/4){
    if (bw == 0){
      float s = 0.f;
      for (int i = lane; i < N_ATOMS; i += 64) s += e_at[i];
      #pragma unroll
      for (int o = 1; o < 64; o <<= 1) s += __shfl_xor(s, o);
      if (lane == 0) out[0] = s;
    }
    return;
  }
  int a = blockIdx.x*4 + bw;
  float pax = pos[3*a], pay = pos[3*a+1], paz = pos[3*a+2];
  int cnt = nb_cnt[a];
  float fx = 0.f, fy = 0.f, fz = 0.f;
  for (int n = lane; n < cnt; n += 64){
    int j = nb_idx[a*MAXNB + n];
    float d = nb_d[a*MAXNB + n];
    float s = edge_s[a*MAXNB + n];
    int cj = nb_cnt[j];
    int lo = 0, hi = cj - 1, p = -1;
    while (lo <= hi){
      int mid = (lo + hi) >> 1;
      int v = nb_idx[j*MAXNB + mid];
      if (v == a){ p = mid; break; }
      if (v < a) lo = mid + 1; else hi = mid - 1;
    }
    float sj = (p >= 0) ? edge_s[j*MAXNB + p] : 0.0f;
    float coef = (s + sj)/d;
    float dx = pax - pos[3*j], dy = pay - pos[3*j+1], dz = paz - pos[3*j+2];
    fx -= coef*dx; fy -= coef*dy; fz -= coef*dz;
  }
  #pragma unroll
  for (int o = 1; o < 64; o <<= 1){
    fx += __shfl_xor(fx, o); fy += __shfl_xor(fy, o); fz += __shfl_xor(fz, o);
  }
  if (lane == 0){
    out[1 + 3*a + 0] = fx;
    out[1 + 3*a + 1] = fy;
    out[1 + 3*a + 2] = fz;
  }
}

extern "C" void kernel_launch(void* const* d_in, const int* in_sizes, int n_in,
                              void* d_out, int out_size, void* d_ws, size_t ws_size,
                              hipStream_t stream){
  const float* pos   = (const float*)d_in[0];
  const int*   z     = (const int*)  d_in[1];
  const float* embed = (const float*)d_in[2];
  const float* W1    = (const float*)d_in[3];
  const float* W2    = (const float*)d_in[4];
  const float* Wr1   = (const float*)d_in[5];
  const float* Wr2   = (const float*)d_in[6];
  float* out = (float*)d_out;

  float* ws = (float*)d_ws;
  float* m1   = ws;            // NF
  float* m2   = m1 + NF;       // NF
  float* Bbuf = m2 + NF;       // NKF slot: dA2 bf16
  float* Cbuf = Bbuf + NKF;    // NKF slot: dA1 bf16
  unsigned short* dA2bf = (unsigned short*)Bbuf;
  unsigned short* dA1bf = (unsigned short*)Cbuf;
  unsigned short* Afrag = (unsigned short*)(Cbuf + NKF);  // NKF bf16
  unsigned short* Gfrag = Afrag + NKF;                    // NF bf16
  unsigned short* h0bf = Gfrag + NF;   // NF bf16
  unsigned short* h1bf = h0bf + NF;    // NF bf16
  unsigned short* h2bf = h1bf + NF;    // NF bf16
  unsigned short* g2bf = h2bf + NF;    // NF bf16
  unsigned short* WF1  = g2bf + NF;    // KFF bf16 each
  unsigned short* WF2  = WF1 + KFF;
  unsigned short* WDF2 = WF2 + KFF;
  unsigned short* WTF1 = WDF2 + KFF;
  unsigned short* WTF2 = WTF1 + KFF;
  unsigned short* Wr1F  = WTF2 + KFF;  // FF bf16
  unsigned short* Wr1TF = Wr1F + FF;   // FF bf16
  float* e_at = (float*)(Wr1TF + FF);  // N
  float* nb_d = e_at + N_ATOMS;        // N*MAXNB
  float* edge_s = nb_d + N_ATOMS*MAXNB;// N*MAXNB
  float* rbf  = edge_s + N_ATOMS*MAXNB;         // N*MAXNB*8
  float* drbf = rbf + N_ATOMS*MAXNB*8;          // N*MAXNB*8
  int* nb_idx = (int*)(drbf + N_ATOMS*MAXNB*8); // N*MAXNB
  int* nb_cnt = nb_idx + N_ATOMS*MAXNB;         // N

  // prep: nb+rbf (2048) | wprep (64) | embed (2048)
  k_prep<<<2048 + 64 + NF/256, 256, 0, stream>>>(pos, z, embed, W1, W2, Wr1,
        nb_idx, nb_d, nb_cnt, rbf, drbf,
        WF1, WF2, WDF2, WTF1, WTF2, Wr1F, Wr1TF, h0bf);

  // forward layer 1 (agg via LDS-staged embed table)
  k_agg0<<<N_ATOMS, 256, 0, stream>>>(z, embed, nb_idx, rbf, nb_cnt, Afrag);
  k_mgemm_fwd<<<dim3(256, 2), 256, 0, stream>>>(Afrag, WF1, h0bf, m1, m1, h1bf, Gfrag, 0);
  // forward layer 2
  k_agg<<<N_ATOMS, 256, 0, stream>>>(h1bf, nb_idx, rbf, nb_cnt, Afrag);
  k_mgemm_fwd<<<dim3(256, 2), 256, 0, stream>>>(Afrag, WF2, h1bf, m2, m2, h2bf, Gfrag, 0);

  // MFMA readout (4 waves/block; writes e_at, g2 bf16 + frag)
  k_readout<<<N_ATOMS/16, 256, 0, stream>>>(h2bf, m2, Wr1F, Wr1TF, Wr2, e_at, g2bf, Gfrag);

  // backward: dA2 GEMM + Agg2 in one launch
  k_bwdmix<<<512 + N_ATOMS, 256, 0, stream>>>(Gfrag, WTF2, dA2bf,
        g2bf, nb_idx, rbf, nb_cnt, Afrag);
  k_mgemm_fwd<<<dim3(256, 2), 256, 0, stream>>>(Afrag, WDF2, g2bf, m1, m1, h2bf, Gfrag, 1); // g1 -> Gfrag
  k_mgemm_bwd<<<512, 256, 0, stream>>>(Gfrag, WTF1, dA1bf);       // dA1
  k_edge<<<N_ATOMS, 256, 0, stream>>>(dA2bf, dA1bf, h1bf, h0bf, drbf, nb_idx, nb_cnt, edge_s);
  k_force<<<N_ATOMS/4 + 1, 256, 0, stream>>>(pos, nb_idx, nb_d, nb_cnt, edge_s, e_at, out);
}

// Round 21
// 168.662 us; speedup vs baseline: 1.0256x; 1.0256x over previous
//
#include <hip/hip_runtime.h>
#include <math.h>

#define N_ATOMS 4096
#define F 128
#define K 8
#define KF 1024           // K*F
#define KFF 131072        // K*F*F
#define FF 16384          // F*F
#define NF 524288         // N*F
#define NKF 4194304       // N*K*F
#define MAXNB 128
#define RMAX 5.0f
#define RMAX2 25.0f
#define GAMMA 2.56f       // (K/RMAX)^2
#define MU_STEP 0.714285714285714f  // RMAX/(K-1)
#define PI_F 3.14159265358979323846f
#define POR (PI_F / RMAX)

typedef __bf16 bf16x8_t __attribute__((ext_vector_type(8)));
typedef float f32x4_t __attribute__((ext_vector_type(4)));
typedef unsigned short u16x8_t __attribute__((ext_vector_type(8)));
typedef unsigned short u16x4_t __attribute__((ext_vector_type(4)));

__device__ __forceinline__ float sigm(float x){ return 1.0f/(1.0f + expf(-x)); }
__device__ __forceinline__ unsigned short f2bf(float x){
  unsigned int u = __float_as_uint(x);
  u += 0x7fff + ((u >> 16) & 1);
  return (unsigned short)(u >> 16);
}

// ======================= device bodies ======================================

// agg: A[a,k,f] = sum_n rbf_k(d_an) h[j_n,f] -> bf16 A-fragments (h in bf16)
__device__ __forceinline__ void agg_body(int a, int t,
        const unsigned short* __restrict__ h_in, const int* __restrict__ nb_idx,
        const float* __restrict__ rbf, const int* __restrict__ nb_cnt,
        unsigned short* __restrict__ Af){
  int grp = t >> 6, lane = t & 63;
  __shared__ int s_j[MAXNB];
  __shared__ float s_acc[4][8][128];
  int cnt = nb_cnt[a];
  for (int idx = t; idx < cnt; idx += 256) s_j[idx] = nb_idx[a*MAXNB + idx];
  __syncthreads();
  float2 acc[8];
  #pragma unroll
  for (int k = 0; k < 8; k++) acc[k] = {0.f, 0.f};
  const float4* rb = (const float4*)(rbf + (size_t)a*MAXNB*8);
  for (int n = grp; n < cnt; n += 4){
    unsigned int pv = *(const unsigned int*)&h_in[(size_t)s_j[n]*F + lane*2];
    float hx = __uint_as_float(pv << 16);
    float hy = __uint_as_float(pv & 0xffff0000u);
    float4 r0 = rb[n*2], r1 = rb[n*2+1];
    acc[0].x += r0.x*hx; acc[0].y += r0.x*hy;
    acc[1].x += r0.y*hx; acc[1].y += r0.y*hy;
    acc[2].x += r0.z*hx; acc[2].y += r0.z*hy;
    acc[3].x += r0.w*hx; acc[3].y += r0.w*hy;
    acc[4].x += r1.x*hx; acc[4].y += r1.x*hy;
    acc[5].x += r1.y*hx; acc[5].y += r1.y*hy;
    acc[6].x += r1.z*hx; acc[6].y += r1.z*hy;
    acc[7].x += r1.w*hx; acc[7].y += r1.w*hy;
  }
  #pragma unroll
  for (int k = 0; k < 8; k++)
    *(float2*)&s_acc[grp][k][lane*2] = acc[k];
  __syncthreads();
  int k = t >> 5, q = t & 31;
  int f0 = q*4;
  float v[4];
  #pragma unroll
  for (int i = 0; i < 4; i++){
    int f = f0 + i;
    v[i] = s_acc[0][k][f] + s_acc[1][k][f] + s_acc[2][k][f] + s_acc[3][k][f];
  }
  int lf = (a & 15) | (((f0 >> 3) & 3) << 4);
  int kc = k*4 + (f0 >> 5);
  size_t flat = (size_t)(a >> 4)*16384 + ((size_t)kc*64 + lf)*8 + (f0 & 7);
  u16x4_t o;
  o[0] = f2bf(v[0]); o[1] = f2bf(v[1]); o[2] = f2bf(v[2]); o[3] = f2bf(v[3]);
  *(u16x4_t*)(Af + flat) = o;
}

__device__ __forceinline__ void mgemm_bwd_body(int bx, int t,
        const unsigned short* __restrict__ Gf, const unsigned short* __restrict__ Bf,
        unsigned short* __restrict__ dAbf){
  int l = t & 63, w = t >> 6;
  int rtile = (bx & 63)*4 + w;
  int nt0 = (bx >> 6)*8;
  f32x4_t acc[8];
  #pragma unroll
  for (int i = 0; i < 8; i++) acc[i] = (f32x4_t){0.f,0.f,0.f,0.f};
  const unsigned short* Ab = Gf + (size_t)rtile*2048 + l*8;
  const unsigned short* Bb = Bf + l*8;
  #pragma unroll
  for (int kc = 0; kc < 4; kc++){
    bf16x8_t a = *(const bf16x8_t*)(Ab + kc*512);
    #pragma unroll
    for (int nt = 0; nt < 8; nt++){
      bf16x8_t b = *(const bf16x8_t*)(Bb + (kc*64 + nt0 + nt)*512);
      acc[nt] = __builtin_amdgcn_mfma_f32_16x16x32_bf16(a, b, acc[nt], 0, 0, 0);
    }
  }
  int row0 = rtile*16 + (l >> 4)*4;
  int col = l & 15;
  #pragma unroll
  for (int nt = 0; nt < 8; nt++){
    #pragma unroll
    for (int r = 0; r < 4; r++)
      dAbf[(size_t)(row0+r)*1024 + (nt0+nt)*16 + col] = f2bf(acc[nt][r]);
  }
}

// ======================= kernels ============================================

// ---- mega-prep: [0,2048) nb scan (2 atoms x 2 j-half waves) + rbf tail;
//                 [2048,2112) wprep; rest embed
__global__ __launch_bounds__(256) void k_prep(const float* __restrict__ pos,
        const int* __restrict__ z, const float* __restrict__ embed,
        const float* __restrict__ W1, const float* __restrict__ W2,
        const float* __restrict__ Wr1,
        int* __restrict__ nb_idx, float* __restrict__ nb_d, int* __restrict__ nb_cnt,
        float* __restrict__ rbf, float* __restrict__ drbf,
        unsigned short* __restrict__ WF1, unsigned short* __restrict__ WF2,
        unsigned short* __restrict__ WDF2, unsigned short* __restrict__ WTF1,
        unsigned short* __restrict__ WTF2, unsigned short* __restrict__ Wr1F,
        unsigned short* __restrict__ Wr1TF,
        float* __restrict__ h0, unsigned short* __restrict__ h0bf){
  int t = threadIdx.x;
  if (blockIdx.x < 2048){
    int w2 = t >> 7;          // atom sub-index
    int half = (t >> 6) & 1;  // j half
    int lane = t & 63;
    int i = blockIdx.x*2 + w2;
    __shared__ float spx[2][256], spy[2][256], spz[2][256], ssq[2][256];
    __shared__ int s_jl[2][2][128];
    __shared__ float s_dl[2][2][128];
    __shared__ int s_cnt[2][2];
    float pix = pos[3*i], piy = pos[3*i+1], piz = pos[3*i+2];
    float sqi = pix*pix + piy*piy + piz*piz;
    int count = 0;
    for (int it = 0; it < 8; it++){
      __syncthreads();
      {
        int j0 = it*256 + t;
        float px = pos[3*j0], py = pos[3*j0+1], pz = pos[3*j0+2];
        spx[0][t] = px; spy[0][t] = py; spz[0][t] = pz;
        ssq[0][t] = px*px + py*py + pz*pz;
        int j1 = 2048 + it*256 + t;
        px = pos[3*j1]; py = pos[3*j1+1]; pz = pos[3*j1+2];
        spx[1][t] = px; spy[1][t] = py; spz[1][t] = pz;
        ssq[1][t] = px*px + py*py + pz*pz;
      }
      __syncthreads();
      #pragma unroll
      for (int c = 0; c < 4; c++){
        int jj = c*64 + lane;
        int j = half*2048 + it*256 + jj;
        float dot = pix*spx[half][jj] + piy*spy[half][jj] + piz*spz[half][jj];
        float d2 = sqi + ssq[half][jj] - 2.0f*dot;
        bool pred = (j != i) && (d2 > 0.0f) && (d2 < RMAX2);
        unsigned long long m = __ballot(pred);
        int off = __popcll(m & ((1ull << lane) - 1ull));
        if (pred){
          int p = count + off;
          if (p < 128){ s_jl[w2][half][p] = j; s_dl[w2][half][p] = sqrtf(d2); }
        }
        count += __popcll(m);
      }
    }
    if (lane == 0) s_cnt[w2][half] = count;
    __syncthreads();
    int c0 = s_cnt[w2][0]; if (c0 > 128) c0 = 128;
    int c1 = s_cnt[w2][1]; if (c1 > 128) c1 = 128;
    int cc = c0 + c1; if (cc > MAXNB) cc = MAXNB;
    int tia = t & 127;
    if (tia == 0) nb_cnt[i] = cc;
    for (int n = tia; n < cc; n += 128){
      int j; float d;
      if (n < c0){ j = s_jl[w2][0][n]; d = s_dl[w2][0][n]; }
      else       { j = s_jl[w2][1][n - c0]; d = s_dl[w2][1][n - c0]; }
      nb_idx[i*MAXNB + n] = j;
      nb_d[i*MAXNB + n] = d;
      float ph = POR*d;
      float cph, sph;
      __sincosf(ph, &sph, &cph);
      float env = 0.5f*(cph + 1.0f);
      float denv = -0.5f*POR*sph;
      float rr[8], dd[8];
      #pragma unroll
      for (int k = 0; k < 8; k++){
        float dm = d - MU_STEP*(float)k;
        float G = expf(-GAMMA*dm*dm);
        rr[k] = G*env;
        dd[k] = G*(-2.0f*GAMMA*dm*env + denv);
      }
      float4* rb = (float4*)(rbf + ((size_t)i*MAXNB + n)*8);
      rb[0] = {rr[0],rr[1],rr[2],rr[3]};
      rb[1] = {rr[4],rr[5],rr[6],rr[7]};
      float4* db = (float4*)(drbf + ((size_t)i*MAXNB + n)*8);
      db[0] = {dd[0],dd[1],dd[2],dd[3]};
      db[1] = {dd[4],dd[5],dd[6],dd[7]};
    }
    return;
  }
  if (blockIdx.x >= 2112){
    int idx = (blockIdx.x - 2112)*256 + t;
    int i = idx >> 7, f = idx & 127;
    float v = embed[z[i]*F + f];
    h0[idx] = v;
    h0bf[idx] = f2bf(v);
    return;
  }
  int idx = (blockIdx.x - 2048)*256 + t;   // 0..16383
  int l = idx & 63;
  int hi = idx >> 6;
  {
    int kc = hi >> 3, nt = hi & 7;
    int kfb = kc*32 + ((l>>4)&3)*8;
    int g = nt*16 + (l&15);
    u16x8_t v1, v2, vd;
    #pragma unroll
    for (int j = 0; j < 8; j++){
      int kf = kfb + j;
      v1[j] = f2bf(W1[kf*128 + g]);
      v2[j] = f2bf(W2[kf*128 + g]);
      vd[j] = f2bf(W2[(kf>>7)*FF + g*F + (kf&127)]);
    }
    *(u16x8_t*)(WF1 + idx*8) = v1;
    *(u16x8_t*)(WF2 + idx*8) = v2;
    *(u16x8_t*)(WDF2 + idx*8) = vd;
  }
  {
    int kc = hi >> 6, nt = hi & 63;
    int gb = kc*32 + ((l>>4)&3)*8;
    int kf = nt*16 + (l&15);
    u16x8_t t1, t2;
    #pragma unroll
    for (int j = 0; j < 8; j++){
      int g = gb + j;
      t1[j] = f2bf(W1[kf*128 + g]);
      t2[j] = f2bf(W2[kf*128 + g]);
    }
    *(u16x8_t*)(WTF1 + idx*8) = t1;
    *(u16x8_t*)(WTF2 + idx*8) = t2;
  }
  {
    int m = idx >> 9;
    int ll = (idx >> 3) & 63;
    int j = idx & 7;
    int kc = m >> 3, nt = m & 7;
    int kf = kc*32 + ((ll>>4)&3)*8 + j;
    int g = nt*16 + (ll&15);
    Wr1F[idx]  = f2bf(Wr1[kf*128 + g]);
    Wr1TF[idx] = f2bf(Wr1[g*128 + kf]);
  }
}

// ---- standalone agg --------------------------------------------------------
__global__ __launch_bounds__(256) void k_agg(const unsigned short* __restrict__ h_in,
        const int* __restrict__ nb_idx, const float* __restrict__ rbf,
        const int* __restrict__ nb_cnt, unsigned short* __restrict__ Af){
  agg_body(blockIdx.x, threadIdx.x, h_in, nb_idx, rbf, nb_cnt, Af);
}

// ---- merged: [0,512) mgemm_bwd(dA2); [512, 4608) agg(g2bf) -----------------
__global__ __launch_bounds__(256) void k_bwdmix(const unsigned short* __restrict__ Gf,
        const unsigned short* __restrict__ Bf, unsigned short* __restrict__ dAbf,
        const unsigned short* __restrict__ g2bf, const int* __restrict__ nb_idx,
        const float* __restrict__ rbf, const int* __restrict__ nb_cnt,
        unsigned short* __restrict__ Af){
  if (blockIdx.x < 512){
    mgemm_bwd_body(blockIdx.x, threadIdx.x, Gf, Bf, dAbf);
    return;
  }
  agg_body(blockIdx.x - 512, threadIdx.x, g2bf, nb_idx, rbf, nb_cnt, Af);
}

// ---- standalone mgemm_bwd --------------------------------------------------
__global__ __launch_bounds__(256) void k_mgemm_bwd(const unsigned short* __restrict__ Gf,
        const unsigned short* __restrict__ Bf, unsigned short* __restrict__ dAbf){
  mgemm_bwd_body(blockIdx.x, threadIdx.x, Gf, Bf, dAbf);
}

// ---- full-K MFMA GEMM fwd-shape + fused epilogue ---------------------------
__global__ __launch_bounds__(256) void k_mgemm_fwd(const unsigned short* __restrict__ Af,
        const unsigned short* __restrict__ Bf, const float* __restrict__ addv,
        const float* __restrict__ msrc, float* __restrict__ out_m,
        float* __restrict__ out_h, unsigned short* __restrict__ out_hbf,
        unsigned short* __restrict__ out_frag, int mode){
  int t = threadIdx.x;
  int l = t & 63, w = t >> 6;
  int rtile = blockIdx.x;
  int nt = blockIdx.y*4 + w;
  f32x4_t accA = (f32x4_t){0.f,0.f,0.f,0.f};
  f32x4_t accB = (f32x4_t){0.f,0.f,0.f,0.f};
  const unsigned short* Ab = Af + (size_t)rtile*16384 + l*8;
  const unsigned short* Bb = Bf + l*8;
  #pragma unroll
  for (int kc = 0; kc < 32; kc += 2){
    bf16x8_t a0 = *(const bf16x8_t*)(Ab + kc*512);
    bf16x8_t b0 = *(const bf16x8_t*)(Bb + (kc*8 + nt)*512);
    bf16x8_t a1 = *(const bf16x8_t*)(Ab + (kc+1)*512);
    bf16x8_t b1 = *(const bf16x8_t*)(Bb + ((kc+1)*8 + nt)*512);
    accA = __builtin_amdgcn_mfma_f32_16x16x32_bf16(a0, b0, accA, 0, 0, 0);
    accB = __builtin_amdgcn_mfma_f32_16x16x32_bf16(a1, b1, accB, 0, 0, 0);
  }
  f32x4_t acc = accA + accB;
  int row0 = rtile*16 + (l >> 4)*4;
  int col = nt*16 + (l & 15);
  if (mode == 0){
    #pragma unroll
    for (int r = 0; r < 4; r++){
      int i = row0 + r;
      float m = acc[r] + addv[(size_t)i*F + col];
      out_m[(size_t)i*F + col] = m;
      float h = m*sigm(m);
      out_h[(size_t)i*F + col] = h;
      out_hbf[(size_t)i*F + col] = f2bf(h);
    }
  } else {
    int kc2 = col >> 5;
    int lfr0 = (((col >> 3) & 3) << 4);
    int jj = col & 7;
    #pragma unroll
    for (int r = 0; r < 4; r++){
      int i = row0 + r;
      float mm = msrc[(size_t)i*F + col];
      float sg = sigm(mm);
      float gv = (acc[r] + addv[(size_t)i*F + col])*(sg*(1.f + mm*(1.f - sg)));
      int lfr = (i & 15) | lfr0;
      size_t flat = (((size_t)(i>>4)*4 + kc2)*64 + lfr)*8 + jj;
      out_frag[flat] = f2bf(gv);
    }
  }
}

// ------- MFMA readout: 256 thr = 4 waves per 16 atoms; waves split nt -------
__global__ __launch_bounds__(256) void k_readout(const unsigned short* __restrict__ h2bf,
        const float* __restrict__ m2, const unsigned short* __restrict__ Wr1F,
        const unsigned short* __restrict__ Wr1TF, const float* __restrict__ Wr2,
        float* __restrict__ e_at, float* __restrict__ g2,
        unsigned short* __restrict__ g2bf, unsigned short* __restrict__ g2frag){
  int a0 = blockIdx.x*16;
  int t = threadIdx.x;
  int wv = t >> 6, l = t & 63;
  int rl = l & 15;
  __shared__ unsigned short sdu[16][136];
  __shared__ float ered[4][16];
  // phase 1: wave wv computes u for nt = wv*2 + {0,1}
  f32x4_t acc[2];
  acc[0] = (f32x4_t){0.f,0.f,0.f,0.f};
  acc[1] = (f32x4_t){0.f,0.f,0.f,0.f};
  #pragma unroll
  for (int kc = 0; kc < 4; kc++){
    bf16x8_t af = *(const bf16x8_t*)(h2bf + (size_t)(a0+rl)*F + kc*32 + ((l>>4)&3)*8);
    #pragma unroll
    for (int q = 0; q < 2; q++){
      int nt = wv*2 + q;
      bf16x8_t bf = *(const bf16x8_t*)(Wr1F + ((kc*8+nt)*64 + l)*8);
      acc[q] = __builtin_amdgcn_mfma_f32_16x16x32_bf16(af, bf, acc[q], 0, 0, 0);
    }
  }
  float epart[4] = {0.f,0.f,0.f,0.f};
  #pragma unroll
  for (int q = 0; q < 2; q++){
    int nt = wv*2 + q;
    float w2 = Wr2[nt*16 + rl];
    #pragma unroll
    for (int r = 0; r < 4; r++){
      float u = acc[q][r];
      float sg = sigm(u);
      epart[r] += u*sg*w2;
      sdu[(l>>4)*4 + r][nt*16 + rl] = f2bf(w2*(sg*(1.f + u*(1.f - sg))));
    }
  }
  #pragma unroll
  for (int o = 1; o < 16; o <<= 1){
    #pragma unroll
    for (int r = 0; r < 4; r++) epart[r] += __shfl_xor(epart[r], o);
  }
  if (rl == 0){
    #pragma unroll
    for (int r = 0; r < 4; r++) ered[wv][(l>>4)*4 + r] = epart[r];
  }
  __syncthreads();
  if (t < 16) e_at[a0 + t] = ered[0][t] + ered[1][t] + ered[2][t] + ered[3][t];
  // phase 2: wave wv computes dh for nt = wv*2 + {0,1}
  f32x4_t acc2[2];
  acc2[0] = (f32x4_t){0.f,0.f,0.f,0.f};
  acc2[1] = (f32x4_t){0.f,0.f,0.f,0.f};
  #pragma unroll
  for (int kc = 0; kc < 4; kc++){
    bf16x8_t af = *(const bf16x8_t*)&sdu[rl][kc*32 + ((l>>4)&3)*8];
    #pragma unroll
    for (int q = 0; q < 2; q++){
      int nt = wv*2 + q;
      bf16x8_t bf = *(const bf16x8_t*)(Wr1TF + ((kc*8+nt)*64 + l)*8);
      acc2[q] = __builtin_amdgcn_mfma_f32_16x16x32_bf16(af, bf, acc2[q], 0, 0, 0);
    }
  }
  #pragma unroll
  for (int q = 0; q < 2; q++){
    int nt = wv*2 + q;
    int g = nt*16 + rl;
    int kc2 = g >> 5;
    int lfr0 = (((g >> 3) & 3) << 4);
    int jj = g & 7;
    #pragma unroll
    for (int r = 0; r < 4; r++){
      int a = a0 + (l>>4)*4 + r;
      float mm = m2[(size_t)a*F + g];
      float sg = sigm(mm);
      float gv = acc2[q][r]*(sg*(1.f + mm*(1.f - sg)));
      g2[(size_t)a*F + g] = gv;
      unsigned short gb = f2bf(gv);
      g2bf[(size_t)a*F + g] = gb;
      int lfr = (a & 15) | lfr0;
      g2frag[(((size_t)(a>>4)*4 + kc2)*64 + lfr)*8 + jj] = gb;
    }
  }
}

// ------- per-edge scalar via MFMA -------------------------------------------
__global__ __launch_bounds__(256) void k_edge(const unsigned short* __restrict__ dA2bf,
        const unsigned short* __restrict__ dA1bf, const unsigned short* __restrict__ h1bf,
        const unsigned short* __restrict__ h0bf, const float* __restrict__ drbf,
        const int* __restrict__ nb_idx, const int* __restrict__ nb_cnt,
        float* __restrict__ edge_s){
  int a = blockIdx.x;
  int t = threadIdx.x;
  int w = t >> 6, l = t & 63;
  __shared__ int s_j[MAXNB];
  int cnt = nb_cnt[a];
  for (int idx = t; idx < cnt; idx += 256) s_j[idx] = nb_idx[a*MAXNB + idx];
  int r = l & 15;
  int sel = (l >> 4) & 3;
  u16x8_t a2u[4], a1u[4];
  #pragma unroll
  for (int kc = 0; kc < 4; kc++){
    u16x8_t v2 = {0,0,0,0,0,0,0,0};
    u16x8_t v1 = {0,0,0,0,0,0,0,0};
    if (r < 8){
      v2 = *(const u16x8_t*)(dA2bf + (size_t)a*KF + r*F + kc*32 + sel*8);
      v1 = *(const u16x8_t*)(dA1bf + (size_t)a*KF + r*F + kc*32 + sel*8);
    }
    a2u[kc] = v2; a1u[kc] = v1;
  }
  __syncthreads();
  for (int n0 = w*16; n0 < cnt; n0 += 64){
    int nl = n0 + r;
    int nls = nl < cnt ? nl : cnt - 1;
    int j = s_j[nls];
    const unsigned short* h1p = h1bf + (size_t)j*F + sel*8;
    const unsigned short* h0p = h0bf + (size_t)j*F + sel*8;
    f32x4_t acc = (f32x4_t){0.f,0.f,0.f,0.f};
    #pragma unroll
    for (int kc = 0; kc < 4; kc++){
      bf16x8_t b = *(const bf16x8_t*)(h1p + kc*32);
      acc = __builtin_amdgcn_mfma_f32_16x16x32_bf16(*(const bf16x8_t*)&a2u[kc], b, acc, 0, 0, 0);
    }
    #pragma unroll
    for (int kc = 0; kc < 4; kc++){
      bf16x8_t b = *(const bf16x8_t*)(h0p + kc*32);
      acc = __builtin_amdgcn_mfma_f32_16x16x32_bf16(*(const bf16x8_t*)&a1u[kc], b, acc, 0, 0, 0);
    }
    int krow = (l >> 4) * 4;
    float part = 0.f;
    if (krow < 8){
      float4 dr = *(const float4*)(drbf + ((size_t)a*MAXNB + nls)*8 + krow);
      part = acc[0]*dr.x + acc[1]*dr.y + acc[2]*dr.z + acc[3]*dr.w;
    }
    part += __shfl_xor(part, 16);
    if (l < 16 && nl < cnt) edge_s[a*MAXNB + nl] = part;
  }
}

// ------- force (4 atoms/block) + energy sum ---------------------------------
__global__ __launch_bounds__(256) void k_force(const float* __restrict__ pos,
        const int* __restrict__ nb_idx, const float* __restrict__ nb_d,
        const int* __restrict__ nb_cnt, const float* __restrict__ edge_s,
        const float* __restrict__ e_at, float* __restrict__ out){
  int bw = threadIdx.x >> 6, lane = threadIdx.x & 63;
  if (blockIdx.x == N_ATOMS/4){
    if (bw == 0){
      float s = 0.f;
      for (int i = lane; i < N_ATOMS; i += 64) s += e_at[i];
      #pragma unroll
      for (int o = 1; o < 64; o <<= 1) s += __shfl_xor(s, o);
      if (lane == 0) out[0] = s;
    }
    return;
  }
  int a = blockIdx.x*4 + bw;
  float pax = pos[3*a], pay = pos[3*a+1], paz = pos[3*a+2];
  int cnt = nb_cnt[a];
  float fx = 0.f, fy = 0.f, fz = 0.f;
  for (int n = lane; n < cnt; n += 64){
    int j = nb_idx[a*MAXNB + n];
    float d = nb_d[a*MAXNB + n];
    float s = edge_s[a*MAXNB + n];
    int cj = nb_cnt[j];
    int lo = 0, hi = cj - 1, p = -1;
    while (lo <= hi){
      int mid = (lo + hi) >> 1;
      int v = nb_idx[j*MAXNB + mid];
      if (v == a){ p = mid; break; }
      if (v < a) lo = mid + 1; else hi = mid - 1;
    }
    float sj = (p >= 0) ? edge_s[j*MAXNB + p] : 0.0f;
    float coef = (s + sj)/d;
    float dx = pax - pos[3*j], dy = pay - pos[3*j+1], dz = paz - pos[3*j+2];
    fx -= coef*dx; fy -= coef*dy; fz -= coef*dz;
  }
  #pragma unroll
  for (int o = 1; o < 64; o <<= 1){
    fx += __shfl_xor(fx, o); fy += __shfl_xor(fy, o); fz += __shfl_xor(fz, o);
  }
  if (lane == 0){
    out[1 + 3*a + 0] = fx;
    out[1 + 3*a + 1] = fy;
    out[1 + 3*a + 2] = fz;
  }
}

extern "C" void kernel_launch(void* const* d_in, const int* in_sizes, int n_in,
                              void* d_out, int out_size, void* d_ws, size_t ws_size,
                              hipStream_t stream){
  const float* pos   = (const float*)d_in[0];
  const int*   z     = (const int*)  d_in[1];
  const float* embed = (const float*)d_in[2];
  const float* W1    = (const float*)d_in[3];
  const float* W2    = (const float*)d_in[4];
  const float* Wr1   = (const float*)d_in[5];
  const float* Wr2   = (const float*)d_in[6];
  float* out = (float*)d_out;

  float* ws = (float*)d_ws;
  float* h0   = ws;            // NF
  float* h1   = h0 + NF;
  float* h2   = h1 + NF;
  float* m1   = h2 + NF;
  float* m2   = m1 + NF;
  float* g2b  = m2 + NF;
  float* Bbuf = g2b + NF;      // NKF slot: dA2 bf16
  float* Cbuf = Bbuf + NKF;    // NKF slot: dA1 bf16
  unsigned short* dA2bf = (unsigned short*)Bbuf;
  unsigned short* dA1bf = (unsigned short*)Cbuf;
  unsigned short* Afrag = (unsigned short*)(Cbuf + NKF);  // NKF bf16
  unsigned short* Gfrag = Afrag + NKF;                    // NF bf16
  unsigned short* h0bf = Gfrag + NF;   // NF bf16
  unsigned short* h1bf = h0bf + NF;    // NF bf16
  unsigned short* h2bf = h1bf + NF;    // NF bf16
  unsigned short* g2bf = h2bf + NF;    // NF bf16
  unsigned short* WF1  = g2bf + NF;    // KFF bf16 each
  unsigned short* WF2  = WF1 + KFF;
  unsigned short* WDF2 = WF2 + KFF;
  unsigned short* WTF1 = WDF2 + KFF;
  unsigned short* WTF2 = WTF1 + KFF;
  unsigned short* Wr1F  = WTF2 + KFF;  // FF bf16
  unsigned short* Wr1TF = Wr1F + FF;   // FF bf16
  float* e_at = (float*)(Wr1TF + FF);  // N
  float* nb_d = e_at + N_ATOMS;        // N*MAXNB
  float* edge_s = nb_d + N_ATOMS*MAXNB;// N*MAXNB
  float* rbf  = edge_s + N_ATOMS*MAXNB;         // N*MAXNB*8
  float* drbf = rbf + N_ATOMS*MAXNB*8;          // N*MAXNB*8
  int* nb_idx = (int*)(drbf + N_ATOMS*MAXNB*8); // N*MAXNB
  int* nb_cnt = nb_idx + N_ATOMS*MAXNB;         // N

  // prep: nb+rbf (2048) | wprep (64) | embed (2048)
  k_prep<<<2048 + 64 + NF/256, 256, 0, stream>>>(pos, z, embed, W1, W2, Wr1,
        nb_idx, nb_d, nb_cnt, rbf, drbf,
        WF1, WF2, WDF2, WTF1, WTF2, Wr1F, Wr1TF, h0, h0bf);

  // forward layer 1
  k_agg<<<N_ATOMS, 256, 0, stream>>>(h0bf, nb_idx, rbf, nb_cnt, Afrag);
  k_mgemm_fwd<<<dim3(256, 2), 256, 0, stream>>>(Afrag, WF1, h0, h0, m1, h1, h1bf, Gfrag, 0);
  // forward layer 2
  k_agg<<<N_ATOMS, 256, 0, stream>>>(h1bf, nb_idx, rbf, nb_cnt, Afrag);
  k_mgemm_fwd<<<dim3(256, 2), 256, 0, stream>>>(Afrag, WF2, h1, h1, m2, h2, h2bf, Gfrag, 0);

  // MFMA readout (4 waves/block; writes e_at, g2 f32 + bf16 + frag)
  k_readout<<<N_ATOMS/16, 256, 0, stream>>>(h2bf, m2, Wr1F, Wr1TF, Wr2, e_at, g2b, g2bf, Gfrag);

  // backward: dA2 GEMM + Agg2 in one launch
  k_bwdmix<<<512 + N_ATOMS, 256, 0, stream>>>(Gfrag, WTF2, dA2bf,
        g2bf, nb_idx, rbf, nb_cnt, Afrag);
  k_mgemm_fwd<<<dim3(256, 2), 256, 0, stream>>>(Afrag, WDF2, g2b, m1, m1, m1, h2bf, Gfrag, 1); // g1 -> Gfrag
  k_mgemm_bwd<<<512, 256, 0, stream>>>(Gfrag, WTF1, dA1bf);       // dA1
  k_edge<<<N_ATOMS, 256, 0, stream>>>(dA2bf, dA1bf, h1bf, h0bf, drbf, nb_idx, nb_cnt, edge_s);
  k_force<<<N_ATOMS/4 + 1, 256, 0, stream>>>(pos, nb_idx, nb_d, nb_cnt, edge_s, e_at, out);
}